// Round 1
// baseline (487.136 us; speedup 1.0000x reference)
//
#include <hip/hip_runtime.h>

// Problem constants
#define B_   4
#define L_   4096
#define D_   1024
#define ROWS (B_ * L_)     // 16384
#define K2   (2 * D_)      // 2048
#define BLD  (ROWS * D_)   // 16777216
#define CH   128           // chunk length for scan
#define NC   32            // chunks per sequence (CH*NC == L_)

typedef __attribute__((ext_vector_type(8))) short s8v;   // 8 x bf16 (4 VGPRs)
typedef __attribute__((ext_vector_type(4))) float f4v;   // 4 x f32 acc

// fp32 -> bf16, round-to-nearest-even (bit manipulation, no header API deps)
__device__ __forceinline__ unsigned short f2bf(float f) {
    unsigned int u = __float_as_uint(f);
    u += 0x7FFFu + ((u >> 16) & 1u);
    return (unsigned short)(u >> 16);
}

__device__ __forceinline__ float sigmoidf_(float v) {
    return 1.0f / (1.0f + __expf(-v));
}

// async 16B global -> LDS (wave-uniform LDS base + lane*16)
__device__ __forceinline__ void llds16(const void* g, void* l) {
    __builtin_amdgcn_global_load_lds(
        (const __attribute__((address_space(1))) unsigned int*)(g),
        (__attribute__((address_space(3))) unsigned int*)(l),
        16, 0, 0);
}

// ---------------- prefix-mean (3 passes) ----------------

// Pass 1: per-chunk partial sums. grid = B*NC*(D/256) = 512 blocks x 256 thr
__global__ void partial_sums(const float* __restrict__ x, float* __restrict__ part) {
    int bid  = blockIdx.x;
    int dblk = bid & 3;
    int c    = (bid >> 2) & 31;
    int b    = bid >> 7;
    int d    = dblk * 256 + threadIdx.x;
    const float* p = x + ((size_t)(b * L_ + c * CH) * D_ + d);
    float s = 0.f;
#pragma unroll 8
    for (int i = 0; i < CH; ++i) s += p[(size_t)i * D_];
    part[(b * NC + c) * D_ + d] = s;
}

// Pass 2: exclusive scan over chunks per (b,d). 4096 threads.
__global__ void scan_chunks(float* __restrict__ part) {
    int idx = blockIdx.x * 256 + threadIdx.x;   // [0,4096)
    int b = idx >> 10, d = idx & 1023;
    float run = 0.f;
#pragma unroll
    for (int c = 0; c < NC; ++c) {
        int o = (b * NC + c) * D_ + d;
        float t = part[o];
        part[o] = run;
        run += t;
    }
}

// Pass 3: recompute in-chunk running sum, write avg (fp32 out) and the
// bf16 GEMM A matrix [ROWS x 2048] = [bf16(x) | bf16(avg)].
__global__ void apply_scan(const float* __restrict__ x, const float* __restrict__ part,
                           float* __restrict__ avg_out, unsigned short* __restrict__ Abf) {
    int bid  = blockIdx.x;
    int dblk = bid & 3;
    int c    = (bid >> 2) & 31;
    int b    = bid >> 7;
    int d    = dblk * 256 + threadIdx.x;
    size_t row0 = (size_t)b * L_ + (size_t)c * CH;
    const float* p = x + (row0 * D_ + d);
    float s = part[(b * NC + c) * D_ + d];
    for (int i = 0; i < CH; ++i) {
        size_t row = row0 + i;
        float xi = p[(size_t)i * D_];
        s += xi;
        float av = s / (float)(c * CH + i + 1);
        avg_out[row * D_ + d]      = av;
        Abf[row * K2 + d]          = f2bf(xi);
        Abf[row * K2 + D_ + d]     = f2bf(av);
    }
}

// W fp32 -> bf16, [2048 x 2048] row-major over e (== B^T layout, K contiguous)
__global__ void conv_w(const float4* __restrict__ W, ushort4* __restrict__ Wbf) {
    int t = blockIdx.x * 256 + threadIdx.x;   // [0, 1048576)
    float4 v = W[t];
    ushort4 o;
    o.x = f2bf(v.x); o.y = f2bf(v.y); o.z = f2bf(v.z); o.w = f2bf(v.w);
    Wbf[t] = o;
}

// ---------------- GEMM (m97 structure) ----------------
// C[row,e] = sum_k A[row,k] * W[e,k].  M=16384, N=2048, K=2048.
// 128x128 tile / block, BK=32, 256 threads (4 waves, 2x2 of 64x64),
// 16x16x32 bf16 MFMA, 4x4 frags per wave, global_load_lds width=16.
__global__ __launch_bounds__(256) void gemm_bt(
        const unsigned short* __restrict__ Abf, const unsigned short* __restrict__ Wbf,
        float* __restrict__ Gin, float* __restrict__ Gf) {
    __shared__ __attribute__((aligned(16))) unsigned short sA[128 * 32];
    __shared__ __attribute__((aligned(16))) unsigned short sB[128 * 32];

    const int t    = threadIdx.x;
    const int w    = t >> 6;
    const int lane = t & 63;
    const int bid  = blockIdx.x;
    const int tileN = bid & 15, tileM = bid >> 4;
    const int row0 = tileM * 128, col0 = tileN * 128;
    const int wm = w >> 1, wn = w & 1;
    const int quad = lane >> 4, lcol = lane & 15;

    f4v acc[4][4];
#pragma unroll
    for (int i = 0; i < 4; ++i)
#pragma unroll
        for (int j = 0; j < 4; ++j)
#pragma unroll
            for (int r = 0; r < 4; ++r) acc[i][j][r] = 0.f;

    // staging: 512 chunks of 16B per tile; chunk c -> row c>>2, col (c&3)*8
    const int c0 = t, c1 = 256 + t;
    const unsigned short* gA0 = Abf + ((size_t)(row0 + (c0 >> 2)) * K2 + (c0 & 3) * 8);
    const unsigned short* gA1 = Abf + ((size_t)(row0 + (c1 >> 2)) * K2 + (c1 & 3) * 8);
    const unsigned short* gB0 = Wbf + ((size_t)(col0 + (c0 >> 2)) * K2 + (c0 & 3) * 8);
    const unsigned short* gB1 = Wbf + ((size_t)(col0 + (c1 >> 2)) * K2 + (c1 & 3) * 8);
    unsigned short* lA0 = &sA[w * 512];
    unsigned short* lA1 = &sA[2048 + w * 512];
    unsigned short* lB0 = &sB[w * 512];
    unsigned short* lB1 = &sB[2048 + w * 512];

    for (int k0 = 0; k0 < K2; k0 += 32) {
        __syncthreads();                       // protect LDS from overwrite
        llds16(gA0 + k0, lA0);
        llds16(gA1 + k0, lA1);
        llds16(gB0 + k0, lB0);
        llds16(gB1 + k0, lB1);
        __syncthreads();                       // drains vmcnt -> data ready

        s8v af[4], bfr[4];
#pragma unroll
        for (int i = 0; i < 4; ++i)
            af[i] = *(const s8v*)&sA[(wm * 64 + i * 16 + lcol) * 32 + quad * 8];
#pragma unroll
        for (int j = 0; j < 4; ++j)
            bfr[j] = *(const s8v*)&sB[(wn * 64 + j * 16 + lcol) * 32 + quad * 8];
#pragma unroll
        for (int i = 0; i < 4; ++i)
#pragma unroll
            for (int j = 0; j < 4; ++j)
                acc[i][j] = __builtin_amdgcn_mfma_f32_16x16x32_bf16(af[i], bfr[j], acc[i][j], 0, 0, 0);
    }

    // C/D layout: col = lane&15, row = quad*4 + reg
    float* Cb; int cb;
    if (tileN < 8) { Cb = Gin; cb = col0; } else { Cb = Gf; cb = col0 - 1024; }
#pragma unroll
    for (int i = 0; i < 4; ++i) {
#pragma unroll
        for (int j = 0; j < 4; ++j) {
            int rr = row0 + wm * 64 + i * 16 + quad * 4;
            int cc = cb + wn * 64 + j * 16 + lcol;
#pragma unroll
            for (int r = 0; r < 4; ++r)
                Cb[(size_t)(rr + r) * D_ + cc] = acc[i][j][r];
        }
    }
}

// ---------------- gating epilogue ----------------
// out = sigmoid(Gin + b[:D])*x + sigmoid(Gf + b[D:])*avg ; Gin aliases out (in-place).
__global__ void gating_epilogue(const float4* Gin, const float4* __restrict__ Gf,
                                const float4* __restrict__ x, const float4* __restrict__ avg,
                                const float* __restrict__ bg, float4* out) {
    int t  = blockIdx.x * 256 + threadIdx.x;   // [0, 4194304)
    int d4 = t & 255;                          // float4 index within a row of 1024
    float4 gi = Gin[t];
    float4 gf = Gf[t];
    float4 xv = x[t];
    float4 av = avg[t];
    float4 b1 = ((const float4*)bg)[d4];
    float4 b2 = ((const float4*)(bg + 1024))[d4];
    float4 o;
    o.x = sigmoidf_(gi.x + b1.x) * xv.x + sigmoidf_(gf.x + b2.x) * av.x;
    o.y = sigmoidf_(gi.y + b1.y) * xv.y + sigmoidf_(gf.y + b2.y) * av.y;
    o.z = sigmoidf_(gi.z + b1.z) * xv.z + sigmoidf_(gf.z + b2.z) * av.z;
    o.w = sigmoidf_(gi.w + b1.w) * xv.w + sigmoidf_(gf.w + b2.w) * av.w;
    out[t] = o;
}

extern "C" void kernel_launch(void* const* d_in, const int* in_sizes, int n_in,
                              void* d_out, int out_size, void* d_ws, size_t ws_size,
                              hipStream_t stream) {
    const float* x  = (const float*)d_in[0];   // [4,4096,1024]
    const float* W  = (const float*)d_in[1];   // [2048,2048]
    const float* bg = (const float*)d_in[2];   // [2048]
    float* out = (float*)d_out;                // [BLD gating | BLD avg]
    float* avg = out + (size_t)BLD;

    char* ws = (char*)d_ws;
    unsigned short* Abf = (unsigned short*)(ws);                      // 64 MB  [16384 x 2048] bf16
    unsigned short* Wbf = (unsigned short*)(ws + (size_t)67108864);   //  8 MB  [2048 x 2048] bf16
    float*          prt = (float*)(ws + (size_t)75497472);            // 0.5 MB [B x NC x D]
    float*          Gf  = (float*)(ws + (size_t)79691776);            // 64 MB  forget-gate pre-act
    // input-gate pre-act lands in d_out's first half (overwritten by epilogue)

    conv_w<<<dim3(4096), dim3(256), 0, stream>>>((const float4*)W, (ushort4*)Wbf);
    partial_sums<<<dim3(512), dim3(256), 0, stream>>>(x, prt);
    scan_chunks<<<dim3(16), dim3(256), 0, stream>>>(prt);
    apply_scan<<<dim3(512), dim3(256), 0, stream>>>(x, prt, avg, Abf);
    gemm_bt<<<dim3(2048), dim3(256), 0, stream>>>(Abf, Wbf, out, Gf);
    gating_epilogue<<<dim3(16384), dim3(256), 0, stream>>>(
        (const float4*)out, (const float4*)Gf, (const float4*)x, (const float4*)avg,
        bg, (float4*)out);
}

// Round 2
// 393.458 us; speedup vs baseline: 1.2381x; 1.2381x over previous
//
#include <hip/hip_runtime.h>

// Problem constants
#define B_   4
#define L_   4096
#define D_   1024
#define ROWS (B_ * L_)     // 16384
#define K2   (2 * D_)      // 2048
#define BLD  (ROWS * D_)   // 16777216
#define CH   128           // chunk length for scan
#define NC   32            // chunks per sequence (CH*NC == L_)

typedef __attribute__((ext_vector_type(8))) short s8v;   // 8 x bf16 (4 VGPRs)
typedef __attribute__((ext_vector_type(4))) float f4v;   // 4 x f32 acc

// fp32 -> bf16, round-to-nearest-even
__device__ __forceinline__ unsigned short f2bf(float f) {
    unsigned int u = __float_as_uint(f);
    u += 0x7FFFu + ((u >> 16) & 1u);
    return (unsigned short)(u >> 16);
}

__device__ __forceinline__ float sigmoidf_(float v) {
    return 1.0f / (1.0f + __expf(-v));
}

// async 16B global -> LDS (wave-uniform LDS base + lane*16)
__device__ __forceinline__ void llds16(const void* g, void* l) {
    __builtin_amdgcn_global_load_lds(
        (const __attribute__((address_space(1))) unsigned int*)(g),
        (__attribute__((address_space(3))) unsigned int*)(l),
        16, 0, 0);
}

// ---------------- prefix-mean (3 passes) ----------------

// Pass 1: per-chunk partial sums. grid = B*NC*(D/256) = 512 blocks x 256 thr
__global__ void partial_sums(const float* __restrict__ x, float* __restrict__ part) {
    int bid  = blockIdx.x;
    int dblk = bid & 3;
    int c    = (bid >> 2) & 31;
    int b    = bid >> 7;
    int d    = dblk * 256 + threadIdx.x;
    const float* p = x + ((size_t)(b * L_ + c * CH) * D_ + d);
    float s = 0.f;
#pragma unroll 8
    for (int i = 0; i < CH; ++i) s += p[(size_t)i * D_];
    part[(b * NC + c) * D_ + d] = s;
}

// Pass 2: exclusive scan over chunks per (b,d). 4096 threads.
__global__ void scan_chunks(float* __restrict__ part) {
    int idx = blockIdx.x * 256 + threadIdx.x;   // [0,4096)
    int b = idx >> 10, d = idx & 1023;
    float run = 0.f;
#pragma unroll
    for (int c = 0; c < NC; ++c) {
        int o = (b * NC + c) * D_ + d;
        float t = part[o];
        part[o] = run;
        run += t;
    }
}

// Pass 3: recompute in-chunk running sum, write avg (fp32 out) and the
// bf16 GEMM A matrix [ROWS x 2048] = [bf16(x) | bf16(avg)].
__global__ void apply_scan(const float* __restrict__ x, const float* __restrict__ part,
                           float* __restrict__ avg_out, unsigned short* __restrict__ Abf) {
    int bid  = blockIdx.x;
    int dblk = bid & 3;
    int c    = (bid >> 2) & 31;
    int b    = bid >> 7;
    int d    = dblk * 256 + threadIdx.x;
    size_t row0 = (size_t)b * L_ + (size_t)c * CH;
    const float* p = x + (row0 * D_ + d);
    float s = part[(b * NC + c) * D_ + d];
    for (int i = 0; i < CH; ++i) {
        size_t row = row0 + i;
        float xi = p[(size_t)i * D_];
        s += xi;
        float av = s / (float)(c * CH + i + 1);
        avg_out[row * D_ + d]      = av;
        Abf[row * K2 + d]          = f2bf(xi);
        Abf[row * K2 + D_ + d]     = f2bf(av);
    }
}

// W fp32 -> bf16, [2048 x 2048] row-major over e (== B^T layout, K contiguous)
__global__ void conv_w(const float4* __restrict__ W, ushort4* __restrict__ Wbf) {
    int t = blockIdx.x * 256 + threadIdx.x;   // [0, 1048576)
    float4 v = W[t];
    ushort4 o;
    o.x = f2bf(v.x); o.y = f2bf(v.y); o.z = f2bf(v.z); o.w = f2bf(v.w);
    Wbf[t] = o;
}

// ---------------- fused GEMM + gating (N-pair) ----------------
// Each block computes the 128x128 tiles for columns [col0,col0+128) of BOTH
// gate halves (e and e+1024), then applies sigmoid gating in-register and
// writes the final gating_outputs tile. 32 MFMAs per barrier pair.
__global__ __launch_bounds__(256, 2) void gemm_gated(
        const unsigned short* __restrict__ Abf, const unsigned short* __restrict__ Wbf,
        const float* __restrict__ x, const float* __restrict__ avg,
        const float* __restrict__ bg, float* __restrict__ out) {
    __shared__ __attribute__((aligned(16))) unsigned short sA [128 * 32];
    __shared__ __attribute__((aligned(16))) unsigned short sB0[128 * 32];
    __shared__ __attribute__((aligned(16))) unsigned short sB1[128 * 32];

    const int t    = threadIdx.x;
    const int w    = t >> 6;
    const int lane = t & 63;
    const int bid  = blockIdx.x;
    const int tileN = bid & 7, tileM = bid >> 3;     // 8 N-pairs x 128 M-tiles
    const int row0 = tileM * 128, col0 = tileN * 128;
    const int wm = w >> 1, wn = w & 1;
    const int quad = lane >> 4, lcol = lane & 15;

    f4v acc0[4][4], acc1[4][4];
#pragma unroll
    for (int i = 0; i < 4; ++i)
#pragma unroll
        for (int j = 0; j < 4; ++j)
#pragma unroll
            for (int r = 0; r < 4; ++r) { acc0[i][j][r] = 0.f; acc1[i][j][r] = 0.f; }

    // staging: 512 chunks of 16B per 128x32 tile; chunk c -> row c>>2, col (c&3)*8
    const int c0 = t, c1 = 256 + t;
    const unsigned short* gA0 = Abf + ((size_t)(row0 + (c0 >> 2)) * K2 + (c0 & 3) * 8);
    const unsigned short* gA1 = Abf + ((size_t)(row0 + (c1 >> 2)) * K2 + (c1 & 3) * 8);
    const unsigned short* gB0a = Wbf + ((size_t)(col0 + (c0 >> 2)) * K2 + (c0 & 3) * 8);
    const unsigned short* gB0b = Wbf + ((size_t)(col0 + (c1 >> 2)) * K2 + (c1 & 3) * 8);
    const unsigned short* gB1a = Wbf + ((size_t)(col0 + 1024 + (c0 >> 2)) * K2 + (c0 & 3) * 8);
    const unsigned short* gB1b = Wbf + ((size_t)(col0 + 1024 + (c1 >> 2)) * K2 + (c1 & 3) * 8);
    unsigned short* lA0  = &sA [w * 512];
    unsigned short* lA1  = &sA [2048 + w * 512];
    unsigned short* lB0a = &sB0[w * 512];
    unsigned short* lB0b = &sB0[2048 + w * 512];
    unsigned short* lB1a = &sB1[w * 512];
    unsigned short* lB1b = &sB1[2048 + w * 512];

    for (int k0 = 0; k0 < K2; k0 += 32) {
        __syncthreads();                       // protect LDS from overwrite
        llds16(gA0  + k0, lA0);
        llds16(gA1  + k0, lA1);
        llds16(gB0a + k0, lB0a);
        llds16(gB0b + k0, lB0b);
        llds16(gB1a + k0, lB1a);
        llds16(gB1b + k0, lB1b);
        __syncthreads();                       // drains vmcnt -> data ready

        s8v af[4], bf0[4], bf1[4];
#pragma unroll
        for (int i = 0; i < 4; ++i)
            af[i] = *(const s8v*)&sA[(wm * 64 + i * 16 + lcol) * 32 + quad * 8];
#pragma unroll
        for (int j = 0; j < 4; ++j) {
            bf0[j] = *(const s8v*)&sB0[(wn * 64 + j * 16 + lcol) * 32 + quad * 8];
            bf1[j] = *(const s8v*)&sB1[(wn * 64 + j * 16 + lcol) * 32 + quad * 8];
        }
#pragma unroll
        for (int i = 0; i < 4; ++i)
#pragma unroll
            for (int j = 0; j < 4; ++j) {
                acc0[i][j] = __builtin_amdgcn_mfma_f32_16x16x32_bf16(af[i], bf0[j], acc0[i][j], 0, 0, 0);
                acc1[i][j] = __builtin_amdgcn_mfma_f32_16x16x32_bf16(af[i], bf1[j], acc1[i][j], 0, 0, 0);
            }
    }

    // Epilogue: gating in-register. C/D layout: col = lane&15, row = quad*4 + reg
    float b1v[4], b2v[4];
#pragma unroll
    for (int j = 0; j < 4; ++j) {
        int cc = col0 + wn * 64 + j * 16 + lcol;
        b1v[j] = bg[cc];
        b2v[j] = bg[1024 + cc];
    }
#pragma unroll
    for (int i = 0; i < 4; ++i) {
#pragma unroll
        for (int j = 0; j < 4; ++j) {
            int rr = row0 + wm * 64 + i * 16 + quad * 4;
            int cc = col0 + wn * 64 + j * 16 + lcol;
#pragma unroll
            for (int r = 0; r < 4; ++r) {
                size_t off = (size_t)(rr + r) * D_ + cc;
                float gi = sigmoidf_(acc0[i][j][r] + b1v[j]);
                float gf = sigmoidf_(acc1[i][j][r] + b2v[j]);
                out[off] = gi * x[off] + gf * avg[off];
            }
        }
    }
}

extern "C" void kernel_launch(void* const* d_in, const int* in_sizes, int n_in,
                              void* d_out, int out_size, void* d_ws, size_t ws_size,
                              hipStream_t stream) {
    const float* x  = (const float*)d_in[0];   // [4,4096,1024]
    const float* W  = (const float*)d_in[1];   // [2048,2048]
    const float* bg = (const float*)d_in[2];   // [2048]
    float* out = (float*)d_out;                // [BLD gating | BLD avg]
    float* avg = out + (size_t)BLD;

    char* ws = (char*)d_ws;
    unsigned short* Abf = (unsigned short*)(ws);                      // 64 MB  [16384 x 2048] bf16
    unsigned short* Wbf = (unsigned short*)(ws + (size_t)67108864);   //  8 MB  [2048 x 2048] bf16
    float*          prt = (float*)(ws + (size_t)75497472);            // 0.5 MB [B x NC x D]

    conv_w<<<dim3(4096), dim3(256), 0, stream>>>((const float4*)W, (ushort4*)Wbf);
    partial_sums<<<dim3(512), dim3(256), 0, stream>>>(x, prt);
    scan_chunks<<<dim3(16), dim3(256), 0, stream>>>(prt);
    apply_scan<<<dim3(512), dim3(256), 0, stream>>>(x, prt, avg, Abf);
    gemm_gated<<<dim3(1024), dim3(256), 0, stream>>>(Abf, Wbf, x, avg, bg, out);
}